// Round 10
// baseline (111.337 us; speedup 1.0000x reference)
//
#include <hip/hip_runtime.h>
#include <cmath>

#define N_J   44      // 4 delta + 8 theta + 32 gamma
#define KDIM  128
#define NCLS  5
#define NT    3       // n-tiles of 16 (44 padded to 48)
#define WCE_OFF (N_J * KDIM)   // ws offset of padded [48][5] classifier weights

typedef __attribute__((ext_vector_type(8))) short bf16x8;
typedef __attribute__((ext_vector_type(4))) float f32x4;

// ---------------------------------------------------------------------------
__device__ __forceinline__ float fast_tanh(float a) {
    float z = fminf(fabsf(a), 15.0f);
    float e = __expf(2.0f * z);
    float t = fmaf(-2.0f, __builtin_amdgcn_rcpf(e + 1.0f), 1.0f);
    return copysignf(t, a);
}

// round-to-nearest-even f32 -> bf16 bits (proven fast path; __float22bfloat162_rn
// measured ~20us slower across R3/R5/R6)
__device__ __forceinline__ short bf16_rne(float f) {
    unsigned u = __builtin_bit_cast(unsigned, f);
    unsigned r = (u + 0x7fffu + ((u >> 16) & 1u)) >> 16;
    return (short)r;
}

// ---------------------------------------------------------------------------
// prep: W_all^T [44][128] f32 at ws[0..5632), Wc_eff padded [48][5] (gamma
// rows scaled by C, rows 44..47 zero) at ws[5632..5872).
__global__ void hc_prep(const float* __restrict__ Wd, const float* __restrict__ Wt,
                        const float* __restrict__ Wg, const float* __restrict__ Wc,
                        float C, float* __restrict__ ws) {
    int tid = blockIdx.x * blockDim.x + threadIdx.x;
    int nthr = gridDim.x * blockDim.x;
    for (int idx = tid; idx < N_J * KDIM; idx += nthr) {
        int j = idx / KDIM, k = idx % KDIM;
        float v;
        if (j < 4)       v = Wd[k * 4  + j];
        else if (j < 12) v = Wt[k * 8  + (j - 4)];
        else             v = Wg[k * 32 + (j - 12)];
        ws[idx] = v;
    }
    for (int idx = tid; idx < 48 * NCLS; idx += nthr) {
        int j = idx / NCLS;
        float v = (j < N_J) ? Wc[idx] * (j >= 12 ? C : 1.0f) : 0.0f;
        ws[WCE_OFF + idx] = v;
    }
}

// ---------------------------------------------------------------------------
// main (hybrid of R7/R9 A-B result): W fragments in VGPRs (inner-loop MFMA
// operands — R9 showed LDS here costs ~26us), classifier weights in LDS
// (epilogue-only, latency-tolerant) to cut persistent VGPRs 108 -> 48 and
// reach 4 waves/SIMD without spill. Swapped-operand mfma(A=W^T, B=x): lane
// (g,n) holds S[row=n][j=16t+4g+r] -> lane-local classifier + 2 shuffles.
__global__ __launch_bounds__(256, 4) void hc_main(
        const float* __restrict__ x, const float* __restrict__ ws,
        const float* __restrict__ bc, float* __restrict__ out, int nrows) {
    __shared__ float sWce[NCLS * NT * 4 * 4]; // [c][t][g][r] float4 chunks, 960B

    const int lane = threadIdx.x & 63;
    const int n    = lane & 15;        // x-row-in-tile
    const int g    = lane >> 4;        // k-group / j-subgroup
    const int wave   = (blockIdx.x * blockDim.x + threadIdx.x) >> 6;
    const int nwaves = (gridDim.x * blockDim.x) >> 6;
    const int ntiles = (nrows + 15) / 16;

    // ---- classifier weights -> LDS (once per workgroup) --------------------
    for (int idx = threadIdx.x; idx < NCLS * 48; idx += 256) {
        // dst layout [c][t][g][r], r fastest
        const int c = idx / 48;
        const int t = (idx >> 4) % 3;
        const int gg = (idx >> 2) & 3;
        const int r = idx & 3;
        const int j = t * 16 + gg * 4 + r;
        sWce[idx] = (j < N_J) ? ws[WCE_OFF + j * NCLS + c] : 0.0f;
    }

    // ---- W^T fragments in VGPRs: lane holds W^T[j = t*16 + n][k-chunk g] ---
    bf16x8 Bf[NT][4];
#pragma unroll
    for (int t = 0; t < NT; ++t) {
        const int j = t * 16 + n;
        const bool jv = (j < N_J);
#pragma unroll
        for (int kb = 0; kb < 4; ++kb) {
            float4 q0 = {0,0,0,0}, q1 = {0,0,0,0};
            if (jv) {
                const float4* wp = reinterpret_cast<const float4*>(ws + j * KDIM + kb * 32 + g * 8);
                q0 = wp[0]; q1 = wp[1];
            }
            bf16x8 bb;
            bb[0] = bf16_rne(q0.x); bb[1] = bf16_rne(q0.y);
            bb[2] = bf16_rne(q0.z); bb[3] = bf16_rne(q0.w);
            bb[4] = bf16_rne(q1.x); bb[5] = bf16_rne(q1.y);
            bb[6] = bf16_rne(q1.z); bb[7] = bf16_rne(q1.w);
            Bf[t][kb] = bb;
        }
    }
    __syncthreads();

    const float4* __restrict__ wc4 = reinterpret_cast<const float4*>(sWce);

    float bcv[NCLS];
#pragma unroll
    for (int c = 0; c < NCLS; ++c) bcv[c] = bc[c];

    for (int tile = wave; tile < ntiles; tile += nwaves) {
        const int rowb = tile * 16;
        const int row  = rowb + n;
        const bool rok = (row < nrows);

        // ---- load x: this lane's 32 floats (row `row`, k = kb*32 + g*8 ..+8)
        float4 raw[8];
        const float4* xp = reinterpret_cast<const float4*>(x)
                           + (unsigned)(row * 32 + g * 2);
#pragma unroll
        for (int kb = 0; kb < 4; ++kb) {
            raw[2*kb]     = rok ? xp[kb * 8]     : float4{0,0,0,0};
            raw[2*kb + 1] = rok ? xp[kb * 8 + 1] : float4{0,0,0,0};
        }

        f32x4 acc[NT];
#pragma unroll
        for (int t = 0; t < NT; ++t) acc[t] = f32x4{0.0f, 0.0f, 0.0f, 0.0f};

#pragma unroll
        for (int kb = 0; kb < 4; ++kb) {
            float f[8] = { raw[2*kb].x, raw[2*kb].y, raw[2*kb].z, raw[2*kb].w,
                           raw[2*kb+1].x, raw[2*kb+1].y, raw[2*kb+1].z, raw[2*kb+1].w };
            bf16x8 av;
#pragma unroll
            for (int i = 0; i < 8; ++i) av[i] = bf16_rne(f[i]);
#pragma unroll
            for (int t = 0; t < NT; ++t)
                acc[t] = __builtin_amdgcn_mfma_f32_16x16x32_bf16(Bf[t][kb], av, acc[t], 0, 0, 0);
        }

        // ---- epilogue: lane-local tanh + classifier, then 2-step reduce ----
        float th[NT][4];
#pragma unroll
        for (int t = 0; t < NT; ++t)
#pragma unroll
            for (int r = 0; r < 4; ++r)
                th[t][r] = fast_tanh(acc[t][r]);

        float o[NCLS];
#pragma unroll
        for (int c = 0; c < NCLS; ++c) {
            float s = 0.0f;
#pragma unroll
            for (int t = 0; t < NT; ++t) {
                const float4 f = wc4[(c * 3 + t) * 4 + g];
                s = fmaf(th[t][0], f.x, fmaf(th[t][1], f.y,
                    fmaf(th[t][2], f.z, fmaf(th[t][3], f.w, s))));
            }
            o[c] = s;
        }
#pragma unroll
        for (int c = 0; c < NCLS; ++c) {
            o[c] += __shfl_xor(o[c], 16);
            o[c] += __shfl_xor(o[c], 32);
        }

        if (g == 0 && rok) {
#pragma unroll
            for (int c = 0; c < NCLS; ++c)
                out[(unsigned)row * NCLS + c] = o[c] + bcv[c];
        }
    }
}

// ---------------------------------------------------------------------------
extern "C" void kernel_launch(void* const* d_in, const int* in_sizes, int n_in,
                              void* d_out, int out_size, void* d_ws, size_t ws_size,
                              hipStream_t stream) {
    const float* x  = (const float*)d_in[0];
    const float* Wd = (const float*)d_in[1];
    const float* Wt = (const float*)d_in[2];
    const float* Wg = (const float*)d_in[3];
    const float* Wc = (const float*)d_in[4];
    const float* bc = (const float*)d_in[5];
    float* out = (float*)d_out;
    const int nrows = in_sizes[0] / KDIM;

    // -------- host: closed-form gamma amplitude scale C (data-independent) ---
    const double dt = 0.01, twopi = 6.283185307179586476925286766559;
    double fd[4], ft[8], pht[8];
    for (int i = 0; i < 4; ++i) fd[i] = 1.0 + 3.0 * (double)i / 3.0;   // 1..4
    for (int i = 0; i < 8; ++i) { ft[i] = 4.0 + 4.0 * (double)i / 7.0; pht[i] = 0.0; }
    double Csum = 0.0;
    for (int k = 0; k < 5; ++k) {
        double s = 0.0, c = 0.0;
        for (int i = 0; i < 4; ++i) { double p = twopi * fd[i] * dt * (double)k; s += sin(p); c += cos(p); }
        double mpd = atan2(s * 0.25, c * 0.25);
        double s2 = 0.0, c2 = 0.0;
        for (int i = 0; i < 8; ++i) { s2 += sin(pht[i]); c2 += cos(pht[i]); }
        double mpt = atan2(s2 * 0.125, c2 * 0.125);
        double pac = 1.0 + 0.3 * cos(mpt);
        Csum += pac * pow(1.0 - dt, 4.0 - (double)k);
        for (int i = 0; i < 8; ++i)
            pht[i] += dt * (twopi * ft[i] + 2.0 * sin(mpd - pht[i]));
    }
    const double Cd = pow(1.0 - dt, 5.0) + dt * Csum;
    const float C = (float)Cd;

    hc_prep<<<23, 256, 0, stream>>>(Wd, Wt, Wg, Wc, C, (float*)d_ws);
    hc_main<<<2048, 256, 0, stream>>>(x, (const float*)d_ws, bc, out, nrows);
}

// Round 11
// 88.856 us; speedup vs baseline: 1.2530x; 1.2530x over previous
//
#include <hip/hip_runtime.h>
#include <cmath>

#define N_J   44      // 4 delta + 8 theta + 32 gamma
#define KDIM  128
#define NCLS  5
#define NT    3       // n-tiles of 16 (44 padded to 48)
#define WCE_OFF (N_J * KDIM)   // ws offset of padded [48][5] classifier weights

typedef __attribute__((ext_vector_type(8))) short bf16x8;
typedef __attribute__((ext_vector_type(4))) float f32x4;

// ---------------------------------------------------------------------------
__device__ __forceinline__ float fast_tanh(float a) {
    float z = fminf(fabsf(a), 15.0f);
    float e = __expf(2.0f * z);
    float t = fmaf(-2.0f, __builtin_amdgcn_rcpf(e + 1.0f), 1.0f);
    return copysignf(t, a);
}

// round-to-nearest-even f32 -> bf16 bits (proven fast path; __float22bfloat162_rn
// measured ~20us slower across R3/R5/R6)
__device__ __forceinline__ short bf16_rne(float f) {
    unsigned u = __builtin_bit_cast(unsigned, f);
    unsigned r = (u + 0x7fffu + ((u >> 16) & 1u)) >> 16;
    return (short)r;
}

// ---------------------------------------------------------------------------
// prep: W_all^T [44][128] f32 at ws[0..5632), Wc_eff padded [48][5] (gamma
// rows scaled by C, rows 44..47 zero) at ws[5632..5872).
__global__ void hc_prep(const float* __restrict__ Wd, const float* __restrict__ Wt,
                        const float* __restrict__ Wg, const float* __restrict__ Wc,
                        float C, float* __restrict__ ws) {
    int tid = blockIdx.x * blockDim.x + threadIdx.x;
    int nthr = gridDim.x * blockDim.x;
    for (int idx = tid; idx < N_J * KDIM; idx += nthr) {
        int j = idx / KDIM, k = idx % KDIM;
        float v;
        if (j < 4)       v = Wd[k * 4  + j];
        else if (j < 12) v = Wt[k * 8  + (j - 4)];
        else             v = Wg[k * 32 + (j - 12)];
        ws[idx] = v;
    }
    for (int idx = tid; idx < 48 * NCLS; idx += nthr) {
        int j = idx / NCLS;
        float v = (j < N_J) ? Wc[idx] * (j >= 12 ? C : 1.0f) : 0.0f;
        ws[WCE_OFF + idx] = v;
    }
}

// ---------------------------------------------------------------------------
// main: R7's proven all-register structure (73.9us; every occupancy-cap
// variant R8-R10 regressed). Deltas vs R7:
//  - load guards replaced by a single row-clamp (nrows%16==0 in practice;
//    clamp keeps general correctness, store still guarded)
//  - non-temporal x loads (268MB zero-reuse stream, skips L3 churn)
//  - grid 1536 (setup amortized over ~5.3 tiles/wave)
__global__ __launch_bounds__(256, 3) void hc_main(
        const float* __restrict__ x, const float* __restrict__ ws,
        const float* __restrict__ bc, float* __restrict__ out, int nrows) {
    const int lane = threadIdx.x & 63;
    const int n    = lane & 15;        // x-row-in-tile
    const int g    = lane >> 4;        // k-group / j-subgroup
    const int wave   = (blockIdx.x * blockDim.x + threadIdx.x) >> 6;
    const int nwaves = (gridDim.x * blockDim.x) >> 6;
    const int ntiles = (nrows + 15) / 16;

    // ---- W^T fragments (A-operand): lane holds W^T[j = t*16 + n][k-chunk g]
    bf16x8 Bf[NT][4];
#pragma unroll
    for (int t = 0; t < NT; ++t) {
        const int j = t * 16 + n;
        const bool jv = (j < N_J);
#pragma unroll
        for (int kb = 0; kb < 4; ++kb) {
            float4 q0 = {0,0,0,0}, q1 = {0,0,0,0};
            if (jv) {
                const float4* wp = reinterpret_cast<const float4*>(ws + j * KDIM + kb * 32 + g * 8);
                q0 = wp[0]; q1 = wp[1];
            }
            bf16x8 bb;
            bb[0] = bf16_rne(q0.x); bb[1] = bf16_rne(q0.y);
            bb[2] = bf16_rne(q0.z); bb[3] = bf16_rne(q0.w);
            bb[4] = bf16_rne(q1.x); bb[5] = bf16_rne(q1.y);
            bb[6] = bf16_rne(q1.z); bb[7] = bf16_rne(q1.w);
            Bf[t][kb] = bb;
        }
    }

    // ---- classifier weights for THIS lane's 12 j-values (j = 16t + 4g + r)
    float wceR[NT][4][NCLS];
#pragma unroll
    for (int t = 0; t < NT; ++t)
#pragma unroll
        for (int r = 0; r < 4; ++r) {
            const int j = t * 16 + g * 4 + r;
#pragma unroll
            for (int c = 0; c < NCLS; ++c)
                wceR[t][r][c] = ws[WCE_OFF + j * NCLS + c];
        }
    float bcv[NCLS];
#pragma unroll
    for (int c = 0; c < NCLS; ++c) bcv[c] = bc[c];

    const f32x4* __restrict__ x4 = reinterpret_cast<const f32x4*>(x);

    for (int tile = wave; tile < ntiles; tile += nwaves) {
        const int rowb = tile * 16;
        const int row  = rowb + n;
        // clamp instead of per-load predication (one v_min; OOB-safe for the
        // generic tail, exact for nrows%16==0 which is the harness case)
        const unsigned rr = min((unsigned)row, (unsigned)(nrows - 1));

        // ---- load x: this lane's 32 floats (row rr, k = kb*32 + g*8 ..+8) --
        f32x4 raw[8];
        const f32x4* xp = x4 + (size_t)rr * 32 + g * 2;
#pragma unroll
        for (int kb = 0; kb < 4; ++kb) {
            raw[2*kb]     = __builtin_nontemporal_load(xp + kb * 8);
            raw[2*kb + 1] = __builtin_nontemporal_load(xp + kb * 8 + 1);
        }

        f32x4 acc[NT];
#pragma unroll
        for (int t = 0; t < NT; ++t) acc[t] = f32x4{0.0f, 0.0f, 0.0f, 0.0f};

#pragma unroll
        for (int kb = 0; kb < 4; ++kb) {
            bf16x8 av;
#pragma unroll
            for (int i = 0; i < 4; ++i) av[i]     = bf16_rne(raw[2*kb][i]);
#pragma unroll
            for (int i = 0; i < 4; ++i) av[4 + i] = bf16_rne(raw[2*kb+1][i]);
#pragma unroll
            for (int t = 0; t < NT; ++t)
                acc[t] = __builtin_amdgcn_mfma_f32_16x16x32_bf16(Bf[t][kb], av, acc[t], 0, 0, 0);
        }

        // ---- epilogue: lane-local tanh + classifier, then 2-step reduce ----
        float o[NCLS];
#pragma unroll
        for (int c = 0; c < NCLS; ++c) o[c] = 0.0f;
#pragma unroll
        for (int t = 0; t < NT; ++t)
#pragma unroll
            for (int r = 0; r < 4; ++r) {
                const float th = fast_tanh(acc[t][r]);
#pragma unroll
                for (int c = 0; c < NCLS; ++c)
                    o[c] = fmaf(th, wceR[t][r][c], o[c]);
            }
#pragma unroll
        for (int c = 0; c < NCLS; ++c) {
            o[c] += __shfl_xor(o[c], 16);
            o[c] += __shfl_xor(o[c], 32);
        }

        if (g == 0 && row < nrows) {
#pragma unroll
            for (int c = 0; c < NCLS; ++c)
                out[(size_t)row * NCLS + c] = o[c] + bcv[c];
        }
    }
}

// ---------------------------------------------------------------------------
extern "C" void kernel_launch(void* const* d_in, const int* in_sizes, int n_in,
                              void* d_out, int out_size, void* d_ws, size_t ws_size,
                              hipStream_t stream) {
    const float* x  = (const float*)d_in[0];
    const float* Wd = (const float*)d_in[1];
    const float* Wt = (const float*)d_in[2];
    const float* Wg = (const float*)d_in[3];
    const float* Wc = (const float*)d_in[4];
    const float* bc = (const float*)d_in[5];
    float* out = (float*)d_out;
    const int nrows = in_sizes[0] / KDIM;

    // -------- host: closed-form gamma amplitude scale C (data-independent) ---
    const double dt = 0.01, twopi = 6.283185307179586476925286766559;
    double fd[4], ft[8], pht[8];
    for (int i = 0; i < 4; ++i) fd[i] = 1.0 + 3.0 * (double)i / 3.0;   // 1..4
    for (int i = 0; i < 8; ++i) { ft[i] = 4.0 + 4.0 * (double)i / 7.0; pht[i] = 0.0; }
    double Csum = 0.0;
    for (int k = 0; k < 5; ++k) {
        double s = 0.0, c = 0.0;
        for (int i = 0; i < 4; ++i) { double p = twopi * fd[i] * dt * (double)k; s += sin(p); c += cos(p); }
        double mpd = atan2(s * 0.25, c * 0.25);
        double s2 = 0.0, c2 = 0.0;
        for (int i = 0; i < 8; ++i) { s2 += sin(pht[i]); c2 += cos(pht[i]); }
        double mpt = atan2(s2 * 0.125, c2 * 0.125);
        double pac = 1.0 + 0.3 * cos(mpt);
        Csum += pac * pow(1.0 - dt, 4.0 - (double)k);
        for (int i = 0; i < 8; ++i)
            pht[i] += dt * (twopi * ft[i] + 2.0 * sin(mpd - pht[i]));
    }
    const double Cd = pow(1.0 - dt, 5.0) + dt * Csum;
    const float C = (float)Cd;

    hc_prep<<<23, 256, 0, stream>>>(Wd, Wt, Wg, Wc, C, (float*)d_ws);
    hc_main<<<1536, 256, 0, stream>>>(x, (const float*)d_ws, bc, out, nrows);
}

// Round 12
// 63.107 us; speedup vs baseline: 1.7643x; 1.4080x over previous
//
#include <hip/hip_runtime.h>
#include <cmath>

#define N_J   44      // 4 delta + 8 theta + 32 gamma
#define KDIM  128
#define NCLS  5
#define NT    3       // n-tiles of 16 (44 padded to 48)
#define WCE_OFF (N_J * KDIM)   // ws offset of padded [48][5] classifier weights

typedef __attribute__((ext_vector_type(8))) short bf16x8;
typedef __attribute__((ext_vector_type(4))) float f32x4;

// ---------------------------------------------------------------------------
__device__ __forceinline__ float fast_tanh(float a) {
    float z = fminf(fabsf(a), 15.0f);
    float e = __expf(2.0f * z);
    float t = fmaf(-2.0f, __builtin_amdgcn_rcpf(e + 1.0f), 1.0f);
    return copysignf(t, a);
}

// round-to-nearest-even f32 -> bf16 bits (proven fast path; __float22bfloat162_rn
// measured ~20us slower across R3/R5/R6)
__device__ __forceinline__ short bf16_rne(float f) {
    unsigned u = __builtin_bit_cast(unsigned, f);
    unsigned r = (u + 0x7fffu + ((u >> 16) & 1u)) >> 16;
    return (short)r;
}

// ---------------------------------------------------------------------------
// prep: W_all^T [44][128] f32 at ws[0..5632), Wc_eff padded [48][5] (gamma
// rows scaled by C, rows 44..47 zero) at ws[5632..5872).
__global__ void hc_prep(const float* __restrict__ Wd, const float* __restrict__ Wt,
                        const float* __restrict__ Wg, const float* __restrict__ Wc,
                        float C, float* __restrict__ ws) {
    int tid = blockIdx.x * blockDim.x + threadIdx.x;
    int nthr = gridDim.x * blockDim.x;
    for (int idx = tid; idx < N_J * KDIM; idx += nthr) {
        int j = idx / KDIM, k = idx % KDIM;
        float v;
        if (j < 4)       v = Wd[k * 4  + j];
        else if (j < 12) v = Wt[k * 8  + (j - 4)];
        else             v = Wg[k * 32 + (j - 12)];
        ws[idx] = v;
    }
    for (int idx = tid; idx < 48 * NCLS; idx += nthr) {
        int j = idx / NCLS;
        float v = (j < N_J) ? Wc[idx] * (j >= 12 ? C : 1.0f) : 0.0f;
        ws[WCE_OFF + idx] = v;
    }
}

// ---------------------------------------------------------------------------
// main: R7's champion all-register structure (73.9us). Deltas vs R7, each
// individually expected-positive (NT loads from R11 dropped — prime suspect
// for the 88.9us regression via no-allocate partial-line re-fetch):
//  - single row-clamp instead of 16 per-load predicates
//  - grid 768 = exactly 3 blocks/CU resident at (256,3): 10.7 tiles/wave,
//    2.7x better setup amortization than R7's 2048-grid, no re-dispatch
__global__ __launch_bounds__(256, 3) void hc_main(
        const float* __restrict__ x, const float* __restrict__ ws,
        const float* __restrict__ bc, float* __restrict__ out, int nrows) {
    const int lane = threadIdx.x & 63;
    const int n    = lane & 15;        // x-row-in-tile
    const int g    = lane >> 4;        // k-group / j-subgroup
    const int wave   = (blockIdx.x * blockDim.x + threadIdx.x) >> 6;
    const int nwaves = (gridDim.x * blockDim.x) >> 6;
    const int ntiles = (nrows + 15) / 16;

    // ---- W^T fragments (A-operand): lane holds W^T[j = t*16 + n][k-chunk g]
    bf16x8 Bf[NT][4];
#pragma unroll
    for (int t = 0; t < NT; ++t) {
        const int j = t * 16 + n;
        const bool jv = (j < N_J);
#pragma unroll
        for (int kb = 0; kb < 4; ++kb) {
            float4 q0 = {0,0,0,0}, q1 = {0,0,0,0};
            if (jv) {
                const float4* wp = reinterpret_cast<const float4*>(ws + j * KDIM + kb * 32 + g * 8);
                q0 = wp[0]; q1 = wp[1];
            }
            bf16x8 bb;
            bb[0] = bf16_rne(q0.x); bb[1] = bf16_rne(q0.y);
            bb[2] = bf16_rne(q0.z); bb[3] = bf16_rne(q0.w);
            bb[4] = bf16_rne(q1.x); bb[5] = bf16_rne(q1.y);
            bb[6] = bf16_rne(q1.z); bb[7] = bf16_rne(q1.w);
            Bf[t][kb] = bb;
        }
    }

    // ---- classifier weights for THIS lane's 12 j-values (j = 16t + 4g + r)
    float wceR[NT][4][NCLS];
#pragma unroll
    for (int t = 0; t < NT; ++t)
#pragma unroll
        for (int r = 0; r < 4; ++r) {
            const int j = t * 16 + g * 4 + r;
#pragma unroll
            for (int c = 0; c < NCLS; ++c)
                wceR[t][r][c] = ws[WCE_OFF + j * NCLS + c];
        }
    float bcv[NCLS];
#pragma unroll
    for (int c = 0; c < NCLS; ++c) bcv[c] = bc[c];

    const f32x4* __restrict__ x4 = reinterpret_cast<const f32x4*>(x);

    for (int tile = wave; tile < ntiles; tile += nwaves) {
        const int rowb = tile * 16;
        const int row  = rowb + n;
        // clamp instead of per-load predication (one v_min; OOB-safe for a
        // generic tail, exact for nrows%16==0 which is the harness case)
        const unsigned rr = min((unsigned)row, (unsigned)(nrows - 1));

        // ---- load x: this lane's 32 floats (row rr, k = kb*32 + g*8 ..+8) --
        f32x4 raw[8];
        const f32x4* xp = x4 + (size_t)rr * 32 + g * 2;
#pragma unroll
        for (int kb = 0; kb < 4; ++kb) {
            raw[2*kb]     = xp[kb * 8];
            raw[2*kb + 1] = xp[kb * 8 + 1];
        }

        f32x4 acc[NT];
#pragma unroll
        for (int t = 0; t < NT; ++t) acc[t] = f32x4{0.0f, 0.0f, 0.0f, 0.0f};

#pragma unroll
        for (int kb = 0; kb < 4; ++kb) {
            bf16x8 av;
#pragma unroll
            for (int i = 0; i < 4; ++i) av[i]     = bf16_rne(raw[2*kb][i]);
#pragma unroll
            for (int i = 0; i < 4; ++i) av[4 + i] = bf16_rne(raw[2*kb+1][i]);
#pragma unroll
            for (int t = 0; t < NT; ++t)
                acc[t] = __builtin_amdgcn_mfma_f32_16x16x32_bf16(Bf[t][kb], av, acc[t], 0, 0, 0);
        }

        // ---- epilogue: lane-local tanh + classifier, then 2-step reduce ----
        float o[NCLS];
#pragma unroll
        for (int c = 0; c < NCLS; ++c) o[c] = 0.0f;
#pragma unroll
        for (int t = 0; t < NT; ++t)
#pragma unroll
            for (int r = 0; r < 4; ++r) {
                const float th = fast_tanh(acc[t][r]);
#pragma unroll
                for (int c = 0; c < NCLS; ++c)
                    o[c] = fmaf(th, wceR[t][r][c], o[c]);
            }
#pragma unroll
        for (int c = 0; c < NCLS; ++c) {
            o[c] += __shfl_xor(o[c], 16);
            o[c] += __shfl_xor(o[c], 32);
        }

        if (g == 0 && row < nrows) {
#pragma unroll
            for (int c = 0; c < NCLS; ++c)
                out[(size_t)row * NCLS + c] = o[c] + bcv[c];
        }
    }
}

// ---------------------------------------------------------------------------
extern "C" void kernel_launch(void* const* d_in, const int* in_sizes, int n_in,
                              void* d_out, int out_size, void* d_ws, size_t ws_size,
                              hipStream_t stream) {
    const float* x  = (const float*)d_in[0];
    const float* Wd = (const float*)d_in[1];
    const float* Wt = (const float*)d_in[2];
    const float* Wg = (const float*)d_in[3];
    const float* Wc = (const float*)d_in[4];
    const float* bc = (const float*)d_in[5];
    float* out = (float*)d_out;
    const int nrows = in_sizes[0] / KDIM;

    // -------- host: closed-form gamma amplitude scale C (data-independent) ---
    const double dt = 0.01, twopi = 6.283185307179586476925286766559;
    double fd[4], ft[8], pht[8];
    for (int i = 0; i < 4; ++i) fd[i] = 1.0 + 3.0 * (double)i / 3.0;   // 1..4
    for (int i = 0; i < 8; ++i) { ft[i] = 4.0 + 4.0 * (double)i / 7.0; pht[i] = 0.0; }
    double Csum = 0.0;
    for (int k = 0; k < 5; ++k) {
        double s = 0.0, c = 0.0;
        for (int i = 0; i < 4; ++i) { double p = twopi * fd[i] * dt * (double)k; s += sin(p); c += cos(p); }
        double mpd = atan2(s * 0.25, c * 0.25);
        double s2 = 0.0, c2 = 0.0;
        for (int i = 0; i < 8; ++i) { s2 += sin(pht[i]); c2 += cos(pht[i]); }
        double mpt = atan2(s2 * 0.125, c2 * 0.125);
        double pac = 1.0 + 0.3 * cos(mpt);
        Csum += pac * pow(1.0 - dt, 4.0 - (double)k);
        for (int i = 0; i < 8; ++i)
            pht[i] += dt * (twopi * ft[i] + 2.0 * sin(mpd - pht[i]));
    }
    const double Cd = pow(1.0 - dt, 5.0) + dt * Csum;
    const float C = (float)Cd;

    hc_prep<<<23, 256, 0, stream>>>(Wd, Wt, Wg, Wc, C, (float*)d_ws);
    hc_main<<<768, 256, 0, stream>>>(x, (const float*)d_ws, bc, out, nrows);
}

// Round 13
// 56.655 us; speedup vs baseline: 1.9652x; 1.1139x over previous
//
#include <hip/hip_runtime.h>
#include <cmath>

#define N_J   44      // 4 delta + 8 theta + 32 gamma
#define KDIM  128
#define NCLS  5
#define NT    3       // n-tiles of 16 (44 padded to 48)
#define WCE_OFF (N_J * KDIM)   // ws offset of padded [48][5] classifier weights

typedef __attribute__((ext_vector_type(8))) short bf16x8;
typedef __attribute__((ext_vector_type(4))) float f32x4;

// ---------------------------------------------------------------------------
__device__ __forceinline__ float fast_tanh(float a) {
    float z = fminf(fabsf(a), 15.0f);
    float e = __expf(2.0f * z);
    float t = fmaf(-2.0f, __builtin_amdgcn_rcpf(e + 1.0f), 1.0f);
    return copysignf(t, a);
}

// round-to-nearest-even f32 -> bf16 bits (proven fast path; __float22bfloat162_rn
// measured ~20us slower across R3/R5/R6)
__device__ __forceinline__ short bf16_rne(float f) {
    unsigned u = __builtin_bit_cast(unsigned, f);
    unsigned r = (u + 0x7fffu + ((u >> 16) & 1u)) >> 16;
    return (short)r;
}

// ---------------------------------------------------------------------------
// prep: W_all^T [44][128] f32 at ws[0..5632), Wc_eff padded [48][5] (gamma
// rows scaled by C, rows 44..47 zero) at ws[5632..5872).
__global__ void hc_prep(const float* __restrict__ Wd, const float* __restrict__ Wt,
                        const float* __restrict__ Wg, const float* __restrict__ Wc,
                        float C, float* __restrict__ ws) {
    int tid = blockIdx.x * blockDim.x + threadIdx.x;
    int nthr = gridDim.x * blockDim.x;
    for (int idx = tid; idx < N_J * KDIM; idx += nthr) {
        int j = idx / KDIM, k = idx % KDIM;
        float v;
        if (j < 4)       v = Wd[k * 4  + j];
        else if (j < 12) v = Wt[k * 8  + (j - 4)];
        else             v = Wg[k * 32 + (j - 12)];
        ws[idx] = v;
    }
    for (int idx = tid; idx < 48 * NCLS; idx += nthr) {
        int j = idx / NCLS;
        float v = (j < N_J) ? Wc[idx] * (j >= 12 ? C : 1.0f) : 0.0f;
        ws[WCE_OFF + idx] = v;
    }
}

// ---------------------------------------------------------------------------
// main: R12 champion (63.1us) + MFMA-classifier epilogue.
// Main GEMM: swapped-operand mfma(A=W^T, B=x): lane (g,n) holds
// S[row=n][j=16t+4g+r] in acc[t][r] — exactly a B-fragment layout in j.
// Classifier: two extra mfma with A = permuted bf16 Wc_eff fragments
// contract all 48 j's across lanes: D[class=4g+r][xrow=n] in acc2[r].
// Removes 60 FMA + 10 shuffles + 60 persistent VGPRs per tile.
__global__ __launch_bounds__(256, 3) void hc_main(
        const float* __restrict__ x, const float* __restrict__ ws,
        const float* __restrict__ bc, float* __restrict__ out, int nrows) {
    const int lane = threadIdx.x & 63;
    const int n    = lane & 15;        // x-row-in-tile / class for A2-frag
    const int g    = lane >> 4;        // k-group / j-subgroup
    const int wave   = (blockIdx.x * blockDim.x + threadIdx.x) >> 6;
    const int nwaves = (gridDim.x * blockDim.x) >> 6;
    const int ntiles = (nrows + 15) / 16;

    // ---- W^T fragments (A-operand): lane holds W^T[j = t*16 + n][k-chunk g]
    bf16x8 Bf[NT][4];
#pragma unroll
    for (int t = 0; t < NT; ++t) {
        const int j = t * 16 + n;
        const bool jv = (j < N_J);
#pragma unroll
        for (int kb = 0; kb < 4; ++kb) {
            float4 q0 = {0,0,0,0}, q1 = {0,0,0,0};
            if (jv) {
                const float4* wp = reinterpret_cast<const float4*>(ws + j * KDIM + kb * 32 + g * 8);
                q0 = wp[0]; q1 = wp[1];
            }
            bf16x8 bb;
            bb[0] = bf16_rne(q0.x); bb[1] = bf16_rne(q0.y);
            bb[2] = bf16_rne(q0.z); bb[3] = bf16_rne(q0.w);
            bb[4] = bf16_rne(q1.x); bb[5] = bf16_rne(q1.y);
            bb[6] = bf16_rne(q1.z); bb[7] = bf16_rne(q1.w);
            Bf[t][kb] = bb;
        }
    }

    // ---- classifier A-fragments: A[class][slot s] = Wce[pi(s)][class] ------
    // slot s = g*8 + i. frag0: pi = 16*(i>>2) + 4g + (i&3)  (j-tiles t=0,1)
    //                   frag1: pi = 32 + 4g + i for i<4, zero-pad i>=4 (t=2)
    bf16x8 af0, af1;
    {
        const int cls = n;
#pragma unroll
        for (int i = 0; i < 8; ++i) {
            const int j0 = 16 * (i >> 2) + 4 * g + (i & 3);
            const float v0 = (cls < NCLS) ? ws[WCE_OFF + j0 * NCLS + cls] : 0.0f;
            af0[i] = bf16_rne(v0);
            const int j1 = 32 + 4 * g + i;   // only i<4 valid
            const float v1 = (cls < NCLS && i < 4) ? ws[WCE_OFF + j1 * NCLS + cls] : 0.0f;
            af1[i] = bf16_rne(v1);
        }
    }

    // ---- bias: classes 0-3 (stored by g==0 lanes) and class 4 (g==1) -------
    const float4 bc03 = { bc[0], bc[1], bc[2], bc[3] };
    const float  bc4  = bc[4];

    const f32x4* __restrict__ x4 = reinterpret_cast<const f32x4*>(x);

    for (int tile = wave; tile < ntiles; tile += nwaves) {
        const int rowb = tile * 16;
        const int row  = rowb + n;
        // clamp instead of per-load predication (exact for nrows%16==0)
        const unsigned rr = min((unsigned)row, (unsigned)(nrows - 1));

        // ---- load x: this lane's 32 floats (row rr, k = kb*32 + g*8 ..+8) --
        f32x4 raw[8];
        const f32x4* xp = x4 + (size_t)rr * 32 + g * 2;
#pragma unroll
        for (int kb = 0; kb < 4; ++kb) {
            raw[2*kb]     = xp[kb * 8];
            raw[2*kb + 1] = xp[kb * 8 + 1];
        }

        f32x4 acc[NT];
#pragma unroll
        for (int t = 0; t < NT; ++t) acc[t] = f32x4{0.0f, 0.0f, 0.0f, 0.0f};

#pragma unroll
        for (int kb = 0; kb < 4; ++kb) {
            bf16x8 av;
#pragma unroll
            for (int i = 0; i < 4; ++i) av[i]     = bf16_rne(raw[2*kb][i]);
#pragma unroll
            for (int i = 0; i < 4; ++i) av[4 + i] = bf16_rne(raw[2*kb+1][i]);
#pragma unroll
            for (int t = 0; t < NT; ++t)
                acc[t] = __builtin_amdgcn_mfma_f32_16x16x32_bf16(Bf[t][kb], av, acc[t], 0, 0, 0);
        }

        // ---- epilogue: tanh (lane-local), then classifier via 2 MFMAs ------
        float th[NT][4];
#pragma unroll
        for (int t = 0; t < NT; ++t)
#pragma unroll
            for (int r = 0; r < 4; ++r)
                th[t][r] = fast_tanh(acc[t][r]);

        bf16x8 thb0, thb1;
#pragma unroll
        for (int i = 0; i < 8; ++i) thb0[i] = bf16_rne(th[i >> 2][i & 3]);
#pragma unroll
        for (int i = 0; i < 8; ++i) thb1[i] = (i < 4) ? bf16_rne(th[2][i]) : (short)0;

        f32x4 acc2 = {0.0f, 0.0f, 0.0f, 0.0f};
        acc2 = __builtin_amdgcn_mfma_f32_16x16x32_bf16(af0, thb0, acc2, 0, 0, 0);
        acc2 = __builtin_amdgcn_mfma_f32_16x16x32_bf16(af1, thb1, acc2, 0, 0, 0);
        // acc2[r] = out-partial for class 4g+r, x-row n

        if (row < nrows) {
            if (g == 0) {
                out[(size_t)row * NCLS + 0] = acc2[0] + bc03.x;
                out[(size_t)row * NCLS + 1] = acc2[1] + bc03.y;
                out[(size_t)row * NCLS + 2] = acc2[2] + bc03.z;
                out[(size_t)row * NCLS + 3] = acc2[3] + bc03.w;
            } else if (g == 1) {
                out[(size_t)row * NCLS + 4] = acc2[0] + bc4;
            }
        }
    }
}

// ---------------------------------------------------------------------------
extern "C" void kernel_launch(void* const* d_in, const int* in_sizes, int n_in,
                              void* d_out, int out_size, void* d_ws, size_t ws_size,
                              hipStream_t stream) {
    const float* x  = (const float*)d_in[0];
    const float* Wd = (const float*)d_in[1];
    const float* Wt = (const float*)d_in[2];
    const float* Wg = (const float*)d_in[3];
    const float* Wc = (const float*)d_in[4];
    const float* bc = (const float*)d_in[5];
    float* out = (float*)d_out;
    const int nrows = in_sizes[0] / KDIM;

    // -------- host: closed-form gamma amplitude scale C (data-independent) ---
    const double dt = 0.01, twopi = 6.283185307179586476925286766559;
    double fd[4], ft[8], pht[8];
    for (int i = 0; i < 4; ++i) fd[i] = 1.0 + 3.0 * (double)i / 3.0;   // 1..4
    for (int i = 0; i < 8; ++i) { ft[i] = 4.0 + 4.0 * (double)i / 7.0; pht[i] = 0.0; }
    double Csum = 0.0;
    for (int k = 0; k < 5; ++k) {
        double s = 0.0, c = 0.0;
        for (int i = 0; i < 4; ++i) { double p = twopi * fd[i] * dt * (double)k; s += sin(p); c += cos(p); }
        double mpd = atan2(s * 0.25, c * 0.25);
        double s2 = 0.0, c2 = 0.0;
        for (int i = 0; i < 8; ++i) { s2 += sin(pht[i]); c2 += cos(pht[i]); }
        double mpt = atan2(s2 * 0.125, c2 * 0.125);
        double pac = 1.0 + 0.3 * cos(mpt);
        Csum += pac * pow(1.0 - dt, 4.0 - (double)k);
        for (int i = 0; i < 8; ++i)
            pht[i] += dt * (twopi * ft[i] + 2.0 * sin(mpd - pht[i]));
    }
    const double Cd = pow(1.0 - dt, 5.0) + dt * Csum;
    const float C = (float)Cd;

    hc_prep<<<23, 256, 0, stream>>>(Wd, Wt, Wg, Wc, C, (float*)d_ws);
    hc_main<<<768, 256, 0, stream>>>(x, (const float*)d_ws, bc, out, nrows);
}